// Round 2
// baseline (836.804 us; speedup 1.0000x reference)
//
#include <hip/hip_runtime.h>
#include <hip/hip_bf16.h>

typedef __attribute__((ext_vector_type(8))) short short8;
typedef __attribute__((ext_vector_type(4))) float floatx4;
typedef __attribute__((ext_vector_type(4))) unsigned short ushort4v;
typedef __attribute__((ext_vector_type(8))) unsigned short ushort8v;

#define N_DIM 12288
#define SPLITK 4
#define KCHUNK (N_DIM / SPLITK)   // 3072
#define KSTEP 64
#define NTILE 64

__device__ __forceinline__ unsigned short f2bf(float f) {
  union { float f; unsigned int i; } x; x.f = f;
  unsigned int r = x.i + 0x7fffu + ((x.i >> 16) & 1u);   // RNE
  return (unsigned short)(r >> 16);
}

// ---------------------------------------------------------------------------
// Kernel 1: phi += obs[64 x Kchunk_s] @ W[Kchunk_s x 12288]  (+bias when s==0)
// fp32 inputs, on-the-fly bf16 conversion, 16x16x32 bf16 MFMA, fp32 atomicAdd
// into the (pre-zeroed) phi buffer. grid=(192,4), block=256 (4 waves).
// ---------------------------------------------------------------------------
__global__ __launch_bounds__(256) void gemm_phi(
    const float* __restrict__ obs, const float* __restrict__ W,
    const float* __restrict__ bias, float* __restrict__ phi)
{
  __shared__ unsigned short A_s[64 * 72];   // A_s[m][k], stride 72 (16B-aligned frags)
  __shared__ unsigned short W_s[64 * 72];   // W_s[n][k] (transposed), stride 72

  const int t = threadIdx.x;
  const int n0 = blockIdx.x * NTILE;
  const int s  = blockIdx.y;
  const int k0 = s * KCHUNK;
  const int lane = t & 63, wv = t >> 6;
  const int l16 = lane & 15, q = lane >> 4;
  const int m0f = 16 * wv;

  floatx4 acc[4];
#pragma unroll
  for (int i = 0; i < 4; i++) acc[i] = (floatx4){0.f, 0.f, 0.f, 0.f};

  const int am = t >> 2, akq = (t & 3) * 16;   // A staging: row, 16-col group
  const int rg = t >> 4, cg = t & 15;          // W staging: 4-row group, 4-col group

  for (int it = 0; it < KCHUNK / KSTEP; ++it) {
    const int kb = k0 + it * KSTEP;
    { // stage A tile 64x64: fp32 -> bf16, row-major K-contiguous
      const float* src = obs + (size_t)am * N_DIM + kb + akq;
      floatx4 f0 = *(const floatx4*)(src);
      floatx4 f1 = *(const floatx4*)(src + 4);
      floatx4 f2 = *(const floatx4*)(src + 8);
      floatx4 f3 = *(const floatx4*)(src + 12);
      ushort8v u0, u1;
#pragma unroll
      for (int i = 0; i < 4; i++) {
        u0[i] = f2bf(f0[i]); u0[4 + i] = f2bf(f1[i]);
        u1[i] = f2bf(f2[i]); u1[4 + i] = f2bf(f3[i]);
      }
      *(ushort8v*)&A_s[am * 72 + akq]     = u0;
      *(ushort8v*)&A_s[am * 72 + akq + 8] = u1;
    }
    { // stage W tile 64x64 transposed: fp32 loads, 4x4 register transpose
      const size_t base = (size_t)(kb + 4 * rg) * N_DIM + (n0 + 4 * cg);
      floatx4 r0 = *(const floatx4*)(W + base);
      floatx4 r1 = *(const floatx4*)(W + base + N_DIM);
      floatx4 r2 = *(const floatx4*)(W + base + 2 * N_DIM);
      floatx4 r3 = *(const floatx4*)(W + base + 3 * N_DIM);
#pragma unroll
      for (int i = 0; i < 4; i++) {
        ushort4v v = { f2bf(r0[i]), f2bf(r1[i]), f2bf(r2[i]), f2bf(r3[i]) };
        *(ushort4v*)&W_s[(4 * cg + i) * 72 + 4 * rg] = v;
      }
    }
    __syncthreads();
#pragma unroll
    for (int kk = 0; kk < 2; ++kk) {
      // A frag: m = m0f+(lane&15), k = 32*kk + 8*(lane>>4) + j  [m89 layout]
      short8 af = *(const short8*)&A_s[(m0f + l16) * 72 + 32 * kk + 8 * q];
#pragma unroll
      for (int nt = 0; nt < 4; ++nt) {
        short8 wf = *(const short8*)&W_s[(16 * nt + l16) * 72 + 32 * kk + 8 * q];
        acc[nt] = __builtin_amdgcn_mfma_f32_16x16x32_bf16(af, wf, acc[nt], 0, 0, 0);
      }
    }
    __syncthreads();
  }
  // epilogue: C/D layout col=lane&15, row=(lane>>4)*4+r  [m89/m91]
#pragma unroll
  for (int nt = 0; nt < 4; ++nt) {
    const int ncol = n0 + 16 * nt + l16;
    const float bv = (s == 0) ? bias[ncol] : 0.f;
#pragma unroll
    for (int r = 0; r < 4; ++r) {
      const int m = m0f + q * 4 + r;
      atomicAdd(&phi[(size_t)m * N_DIM + ncol], acc[nt][r] + bv);
    }
  }
}

// ---------------------------------------------------------------------------
// Kernel 2: per-batch softmax + K=64 VIN sweeps (ping-pong LDS) + argmax +
// patch + MLP. grid = 64 (one block per batch), block = 256 (4x4 cells/thread)
// ---------------------------------------------------------------------------
#define VSTR 76
#define VOFF(h, w) (((h) + 1) * VSTR + (w) + 4)  // halo grid, interior 16B-aligned

__global__ __launch_bounds__(256) void vin_mlp(
    const float* __restrict__ obs, const float* __restrict__ phi,
    const float* __restrict__ w1, const float* __restrict__ b1,
    const float* __restrict__ w2, const float* __restrict__ b2,
    float* __restrict__ out)
{
  __shared__ float Vb[2][66 * VSTR];
  __shared__ float red_v[256];
  __shared__ int   red_i[256];

  const int b = blockIdx.x;
  const int t = threadIdx.x;
  const int ty = t >> 4, tx = t & 15;
  const int h0 = ty * 4, w0 = tx * 4;

  // zero both V buffers (halo must stay 0; interior = V0 = 0)
  for (int i = t; i < 2 * 66 * VSTR; i += 256) (&Vb[0][0])[i] = 0.f;

  // read phi rows -> rin/rout/logits for own 16 cells
  float rin[16], rout[16], lg[16];
#pragma unroll
  for (int r = 0; r < 4; r++) {
    const int j = 3 * ((h0 + r) * 64 + w0);   // 12 contiguous floats, 16B-aligned
    const floatx4* p4 = (const floatx4*)(phi + (size_t)b * N_DIM + j);
    floatx4 x0 = p4[0], x1 = p4[1], x2 = p4[2];
    float f[12];
#pragma unroll
    for (int c = 0; c < 4; c++) { f[c] = x0[c]; f[4 + c] = x1[c]; f[8 + c] = x2[c]; }
#pragma unroll
    for (int c = 0; c < 4; c++) {
      rin [r * 4 + c] = f[3 * c + 0];
      rout[r * 4 + c] = f[3 * c + 1];
      lg  [r * 4 + c] = f[3 * c + 2];
    }
  }

  // block softmax over the 4096 logits
  float lmax = -3.4e38f;
#pragma unroll
  for (int i = 0; i < 16; i++) lmax = fmaxf(lmax, lg[i]);
  __syncthreads();                       // zero-fill done
  red_v[t] = lmax; __syncthreads();
  for (int o = 128; o > 0; o >>= 1) { if (t < o) red_v[t] = fmaxf(red_v[t], red_v[t + o]); __syncthreads(); }
  const float M = red_v[0];
  __syncthreads();
  float p[16]; float esum = 0.f;
#pragma unroll
  for (int i = 0; i < 16; i++) { p[i] = __expf(lg[i] - M); esum += p[i]; }
  red_v[t] = esum; __syncthreads();
  for (int o = 128; o > 0; o >>= 1) { if (t < o) red_v[t] += red_v[t + o]; __syncthreads(); }
  const float inv = 1.f / red_v[0];
  __syncthreads();
#pragma unroll
  for (int i = 0; i < 16; i++) p[i] *= inv;

  // stage rin into Vb[1] interior (halo stays 0) to get shifted-neighbor rin
#pragma unroll
  for (int r = 0; r < 4; r++) {
    floatx4 rr = { rin[r * 4 + 0], rin[r * 4 + 1], rin[r * 4 + 2], rin[r * 4 + 3] };
    *(floatx4*)&Vb[1][VOFF(h0 + r, w0)] = rr;
  }
  __syncthreads();
  // c_d = rin[nbr_d] - rout*(rin[nbr_d] != 0); constant across sweeps
  float cu[16], cdn[16], cl[16], cr[16];
#pragma unroll
  for (int r = 0; r < 4; r++) {
#pragma unroll
    for (int c = 0; c < 4; c++) {
      const int i = r * 4 + c, h = h0 + r, w = w0 + c;
      const float nu = Vb[1][VOFF(h - 1, w)];
      const float nd = Vb[1][VOFF(h + 1, w)];
      const float nl = Vb[1][VOFF(h, w - 1)];
      const float nr = Vb[1][VOFF(h, w + 1)];
      cu [i] = nu - (nu != 0.f ? rout[i] : 0.f);
      cdn[i] = nd - (nd != 0.f ? rout[i] : 0.f);
      cl [i] = nl - (nl != 0.f ? rout[i] : 0.f);
      cr [i] = nr - (nr != 0.f ? rout[i] : 0.f);
    }
  }
  __syncthreads();   // all c_d reads of Vb[1] done before sweep 0 overwrites it

  float v[16];
#pragma unroll
  for (int i = 0; i < 16; i++) v[i] = 0.f;

  // K=64 Jacobi sweeps: V_new = max(V, max_d(p*V[nbr_d] + c_d)), ping-pong LDS
  for (int k = 0; k < 64; k++) {
    const float* Vc = Vb[k & 1];
    float* Vn = Vb[(k & 1) ^ 1];
    const floatx4 top = *(const floatx4*)&Vc[VOFF(h0 - 1, w0)];
    const floatx4 bot = *(const floatx4*)&Vc[VOFF(h0 + 4, w0)];
    float lf[4], rt[4];
#pragma unroll
    for (int r = 0; r < 4; r++) { lf[r] = Vc[VOFF(h0 + r, w0 - 1)]; rt[r] = Vc[VOFF(h0 + r, w0 + 4)]; }
    float nv[16];
#pragma unroll
    for (int r = 0; r < 4; r++) {
#pragma unroll
      for (int c = 0; c < 4; c++) {
        const int i = r * 4 + c;
        const float vu = (r == 0) ? top[c] : v[i - 4];
        const float vd = (r == 3) ? bot[c] : v[i + 4];
        const float vl = (c == 0) ? lf[r] : v[i - 1];
        const float vr = (c == 3) ? rt[r] : v[i + 1];
        const float m1 = fmaxf(fmaf(p[i], vu, cu[i]), fmaf(p[i], vd, cdn[i]));
        const float m2 = fmaxf(fmaf(p[i], vl, cl[i]), fmaf(p[i], vr, cr[i]));
        nv[i] = fmaxf(v[i], fmaxf(m1, m2));
      }
    }
#pragma unroll
    for (int r = 0; r < 4; r++) {
      floatx4 w4 = { nv[r * 4 + 0], nv[r * 4 + 1], nv[r * 4 + 2], nv[r * 4 + 3] };
      *(floatx4*)&Vn[VOFF(h0 + r, w0)] = w4;
    }
#pragma unroll
    for (int i = 0; i < 16; i++) v[i] = nv[i];
    __syncthreads();
  }
  // final V is in Vb[0] (k=63 wrote buffer 0)

  // argmax over obs channel 1 (first-occurrence tie-break = min index)
  float amax = -3.4e38f; int aidx = 0;
#pragma unroll
  for (int r = 0; r < 4; r++) {
#pragma unroll
    for (int c = 0; c < 4; c++) {
      const int cell = (h0 + r) * 64 + (w0 + c);
      const float val = obs[(size_t)b * N_DIM + 3 * cell + 1];
      if (val > amax) { amax = val; aidx = cell; }
    }
  }
  red_v[t] = amax; red_i[t] = aidx;
  __syncthreads();
  for (int o = 128; o > 0; o >>= 1) {
    if (t < o) {
      const float v2 = red_v[t + o]; const int i2 = red_i[t + o];
      if (v2 > red_v[t] || (v2 == red_v[t] && i2 < red_i[t])) { red_v[t] = v2; red_i[t] = i2; }
    }
    __syncthreads();
  }
  const int pos = red_i[0];
  const int pi = pos >> 6, pj = pos & 63;
  __syncthreads();

  // 3x3x4 patch (channels 0..2 = obs, 3 = V; zero-padded borders)
  if (t < 36) {
    const int di = t / 12, rem = t % 12, dj = rem / 4, c4 = rem & 3;
    const int hh = pi - 1 + di, ww = pj - 1 + dj;
    float pv;
    if (c4 < 3) {
      pv = (hh >= 0 && hh < 64 && ww >= 0 && ww < 64)
           ? obs[(size_t)b * N_DIM + 3 * (hh * 64 + ww) + c4] : 0.f;
    } else {
      pv = Vb[0][VOFF(hh, ww)];   // halo provides the zero padding
    }
    red_v[t] = pv;
  }
  __syncthreads();
  if (t < 16) {
    float a = b1[t];
#pragma unroll
    for (int j = 0; j < 36; j++) a = fmaf(red_v[j], w1[j * 16 + t], a);
    red_v[64 + t] = fmaxf(a, 0.f);
  }
  __syncthreads();
  if (t < 4) {
    float a = b2[t];
#pragma unroll
    for (int i = 0; i < 16; i++) a = fmaf(red_v[64 + i], w2[i * 4 + t], a);
    out[b * 4 + t] = a;
  }
}

extern "C" void kernel_launch(void* const* d_in, const int* in_sizes, int n_in,
                              void* d_out, int out_size, void* d_ws, size_t ws_size,
                              hipStream_t stream)
{
  (void)in_sizes; (void)n_in; (void)out_size; (void)ws_size;
  const float* obs  = (const float*)d_in[0];
  const float* phiw = (const float*)d_in[1];
  const float* phib = (const float*)d_in[2];
  const float* w1   = (const float*)d_in[3];
  const float* b1   = (const float*)d_in[4];
  const float* w2   = (const float*)d_in[5];
  const float* b2   = (const float*)d_in[6];
  float* phi = (float*)d_ws;            // 64 * 12288 fp32 = 3.1 MB scratch
  float* out = (float*)d_out;

  hipMemsetAsync(phi, 0, (size_t)64 * N_DIM * sizeof(float), stream);
  hipLaunchKernelGGL(gemm_phi, dim3(N_DIM / NTILE, SPLITK), dim3(256), 0, stream,
                     obs, phiw, phib, phi);
  hipLaunchKernelGGL(vin_mlp, dim3(64), dim3(256), 0, stream,
                     obs, phi, w1, b1, w2, b2, out);
}